// Round 2
// baseline (87.101 us; speedup 1.0000x reference)
//
#include <hip/hip_runtime.h>
#include <math.h>

#define NPIX (8 * 256 * 256)   // B*H*W
#define CC 16                  // C
#define KK 8                   // K
#define PPT 4                  // pixels per thread
#define TPB 256

// Precomputed per-class constants (written by precompute_kernel):
//   g_linv : SC * tril_inverse(L)      [K][C][C] row-major (SC = sqrt(0.5*log2(e)))
//   g_v    : SC * Linv * mean          [K][C]
//   g_c0   : (-0.5*C*log(2pi) - logdet) * log2(e)   [K]
// so that prob_k = exp2( g_c0[k] - sum_i (g_linv[k] x - g_v[k])_i^2 )
__device__ float g_linv[KK * CC * CC];
__device__ float g_v[KK * CC];
__device__ float g_c0[KK];

__global__ void precompute_kernel(const float* __restrict__ st,
                                  const float* __restrict__ mean) {
    __shared__ float linv[KK][CC][CC];
    const int t = threadIdx.x;          // 128 threads: (k, j) = column j of class k
    const int k = t >> 4, j = t & 15;
    const float* L = st + k * CC * CC;  // row-major [C][C], lower triangle used

    // forward substitution: column j of inv(tril(L))
    float col[CC];
#pragma unroll
    for (int i = 0; i < CC; ++i) {
        if (i < j) { col[i] = 0.0f; }
        else {
            float s = (i == j) ? 1.0f : 0.0f;
            for (int m = j; m < i; ++m) s = fmaf(-L[i * CC + m], col[m], s);
            col[i] = s / L[i * CC + i];
        }
        linv[k][i][j] = col[i];
    }
    __syncthreads();

    const float SC = 0.8493218891f;       // sqrt(0.5 * log2(e))
    // thread (k,j) now handles ROW j of class k
#pragma unroll
    for (int c = 0; c < CC; ++c) g_linv[k * CC * CC + j * CC + c] = linv[k][j][c] * SC;
    float v = 0.0f;
#pragma unroll
    for (int c = 0; c < CC; ++c) v = fmaf(linv[k][j][c], mean[k * CC + c], v);
    g_v[k * CC + j] = v * SC;

    if (j == 0) {
        float ld = 0.0f;
#pragma unroll
        for (int i = 0; i < CC; ++i) ld += __logf(fabsf(L[i * CC + i]));
        g_c0[k] = (-14.70301633f - ld) * 1.44269504f;   // -0.5*16*log(2pi) = -14.703016
    }
}

__global__ __launch_bounds__(TPB) void mvn_kernel(const float* __restrict__ x,
                                                  float* __restrict__ out) {
    const int base = blockIdx.x * (TPB * PPT) + threadIdx.x;  // pixels: base + p*TPB

    float xv[PPT][CC];
#pragma unroll
    for (int p = 0; p < PPT; ++p) {
        const float4* xp = reinterpret_cast<const float4*>(x + (size_t)(base + p * TPB) * CC);
#pragma unroll
        for (int q = 0; q < 4; ++q) {
            float4 v = xp[q];
            xv[p][4 * q + 0] = v.x; xv[p][4 * q + 1] = v.y;
            xv[p][4 * q + 2] = v.z; xv[p][4 * q + 3] = v.w;
        }
    }

    float pk[PPT][KK];
#pragma unroll
    for (int k = 0; k < KK; ++k) {
        float quad[PPT] = {0.0f, 0.0f, 0.0f, 0.0f};
#pragma unroll
        for (int i = 0; i < CC; ++i) {
            const float nv = -g_v[k * CC + i];
            float z[PPT];
#pragma unroll
            for (int p = 0; p < PPT; ++p) z[p] = nv;
#pragma unroll
            for (int j = 0; j <= i; ++j) {
                const float Lij = g_linv[k * CC * CC + i * CC + j];
#pragma unroll
                for (int p = 0; p < PPT; ++p) z[p] = fmaf(Lij, xv[p][j], z[p]);
            }
#pragma unroll
            for (int p = 0; p < PPT; ++p) quad[p] = fmaf(z[p], z[p], quad[p]);
        }
        const float c0 = g_c0[k];
#pragma unroll
        for (int p = 0; p < PPT; ++p) pk[p][k] = exp2f(c0 - quad[p]);
    }

#pragma unroll
    for (int p = 0; p < PPT; ++p) {
        float ss = 0.0f;
#pragma unroll
        for (int k = 0; k < KK; ++k) ss = fmaf(pk[p][k], pk[p][k], ss);
        const float inv = rsqrtf(fmaxf(ss, 1e-12f));

        float4* op = reinterpret_cast<float4*>(out + (size_t)(base + p * TPB) * 24);
        const float* xr = xv[p];
        op[0] = make_float4(xr[0],  xr[1],  xr[2],  xr[3]);
        op[1] = make_float4(xr[4],  xr[5],  xr[6],  xr[7]);
        op[2] = make_float4(xr[8],  xr[9],  xr[10], xr[11]);
        op[3] = make_float4(xr[12], xr[13], xr[14], xr[15]);
        op[4] = make_float4(pk[p][0] * inv, pk[p][1] * inv, pk[p][2] * inv, pk[p][3] * inv);
        op[5] = make_float4(pk[p][4] * inv, pk[p][5] * inv, pk[p][6] * inv, pk[p][7] * inv);
    }
}

extern "C" void kernel_launch(void* const* d_in, const int* in_sizes, int n_in,
                              void* d_out, int out_size, void* d_ws, size_t ws_size,
                              hipStream_t stream) {
    const float* x    = (const float*)d_in[0];   // [B,H,W,C] fp32
    const float* mean = (const float*)d_in[1];   // [K,C] fp32
    const float* st   = (const float*)d_in[2];   // [K,C,C] fp32
    float* out = (float*)d_out;                  // [B,H,W,C+K] fp32

    precompute_kernel<<<1, KK * CC, 0, stream>>>(st, mean);
    mvn_kernel<<<NPIX / (TPB * PPT), TPB, 0, stream>>>(x, out);
}